// Round 10
// baseline (2747.337 us; speedup 1.0000x reference)
//
#include <hip/hip_runtime.h>

typedef __attribute__((ext_vector_type(8))) short short8;
typedef __attribute__((ext_vector_type(4))) float f32x4;
typedef __attribute__((ext_vector_type(4))) unsigned u32x4;

__device__ __forceinline__ unsigned short f2bf(float f) {
  unsigned int u = __float_as_uint(f);
  u = (u + 0x7fffu + ((u >> 16) & 1u)) >> 16;
  return (unsigned short)u;
}

__device__ __forceinline__ void xp_store(float* p, float v) { *p = v; }
__device__ __forceinline__ void xp_store(unsigned short* p, float v) { *p = f2bf(v); }
__device__ __forceinline__ float xp_load(const float* p) { return *p; }
__device__ __forceinline__ float xp_load(const unsigned short* p) {
  return __uint_as_float(((unsigned int)*p) << 16);
}

// ---------------- prep: pack W_x and W_h (f32 -> bf16 pairs) ----------------
__global__ void prep_wx(const float* __restrict__ W, unsigned int* __restrict__ Wx2) {
  int i = blockIdx.x * 256 + threadIdx.x;  // 1024*128 dwords
  int g = i >> 7, kk = i & 127;
  float lo = W[(size_t)g * 512 + 256 + 2 * kk];
  float hi = W[(size_t)g * 512 + 256 + 2 * kk + 1];
  Wx2[i] = (unsigned int)f2bf(lo) | ((unsigned int)f2bf(hi) << 16);
}

__global__ void prep_wh(const float* __restrict__ W, unsigned int* __restrict__ Wh2) {
  int i = blockIdx.x * 256 + threadIdx.x;  // 1024*128 dwords
  int r = i >> 7, kk = i & 127;
  float lo = W[(size_t)r * 512 + 2 * kk];
  float hi = W[(size_t)r * 512 + 2 * kk + 1];
  Wh2[i] = (unsigned int)f2bf(lo) | ((unsigned int)f2bf(hi) << 16);
}

// ---------------- GEMM: xp[m][g] = sum_k x[m][k] * Wx[g][k] + b[g] ----------------
template <typename XPT>
__global__ __launch_bounds__(256, 4) void gemm_xp(const float* __restrict__ x,
                                                  const unsigned int* __restrict__ Wx2,
                                                  const float* __restrict__ bias,
                                                  XPT* __restrict__ xp) {
  __shared__ unsigned short As[128][40];
  __shared__ unsigned short Bs[128][40];
  const int m0 = blockIdx.y * 128, n0 = blockIdx.x * 128;
  const int tid = threadIdx.x, lane = tid & 63, w = tid >> 6;
  const int wr = w >> 1, wc = w & 1;
  const int r16 = lane & 15, kq = lane >> 4;
  f32x4 acc[4][4];
#pragma unroll
  for (int m = 0; m < 4; m++)
#pragma unroll
    for (int n = 0; n < 4; n++)
#pragma unroll
      for (int j = 0; j < 4; j++) acc[m][n][j] = 0.f;

  for (int kb = 0; kb < 256; kb += 32) {
    __syncthreads();
#pragma unroll
    for (int i = 0; i < 4; i++) {
      int idx = tid + i * 256;
      int row = idx >> 3, c4 = idx & 7;
      float4 v = *(const float4*)(x + (size_t)(m0 + row) * 256 + kb + c4 * 4);
      ushort4 s;
      s.x = f2bf(v.x); s.y = f2bf(v.y); s.z = f2bf(v.z); s.w = f2bf(v.w);
      *(ushort4*)&As[row][c4 * 4] = s;
    }
#pragma unroll
    for (int i = 0; i < 2; i++) {
      int idx = tid + i * 256;
      int row = idx >> 2, c = idx & 3;
      uint4 v = *(const uint4*)(Wx2 + (size_t)(n0 + row) * 128 + (kb >> 1) + c * 4);
      *(uint4*)&Bs[row][c * 8] = v;
    }
    __syncthreads();
    short8 a[4], bb[4];
#pragma unroll
    for (int m = 0; m < 4; m++)
      a[m] = *(const short8*)&As[wr * 64 + m * 16 + r16][kq * 8];
#pragma unroll
    for (int n = 0; n < 4; n++)
      bb[n] = *(const short8*)&Bs[wc * 64 + n * 16 + r16][kq * 8];
#pragma unroll
    for (int m = 0; m < 4; m++)
#pragma unroll
      for (int n = 0; n < 4; n++)
        acc[m][n] = __builtin_amdgcn_mfma_f32_16x16x32_bf16(a[m], bb[n], acc[m][n], 0, 0, 0);
  }
#pragma unroll
  for (int n = 0; n < 4; n++) {
    int gn = n0 + wc * 64 + n * 16 + r16;
    float bi = bias[gn];
#pragma unroll
    for (int m = 0; m < 4; m++) {
      int gm = m0 + wr * 64 + m * 16 + kq * 4;
#pragma unroll
      for (int j = 0; j < 4; j++) {
        xp_store(&xp[(size_t)(gm + j) * 1024 + gn], acc[m][n][j] + bi);
      }
    }
  }
}

// ---------------- recurrence: ONE BATCH PER CU, LDS-only h exchange ----------------
// 64 WGs x 1024 threads (16 waves/CU, launch_bounds(1024,4) -> 128-VGPR budget).
// Thread (u = tid>>2, p = tid&3) owns unit u's four gate rows over k-slice
// [p*64, p*64+64). Rows f,i,g: 96 bf16-pair dwords loaded via ASM VOLATILE
// global_load_dwordx4 (non-rematerializable def => allocator must keep them
// VGPR-resident; tell: VGPR_Count ~128, was 64 with plain loads). Row o: LDS,
// COLUMN-MAJOR b64 layout wo64[j2][tid] (lane stride 2 dwords -> lanes l and l+16
// share a bank 2-way = free). h state: bf16-pair dwords, 2 slots x 4 p-replicated
// copies at stride 136 dwords; group p reads ITS OWN SLICE at dword 136p+32p+4J ->
// bank (8p+4J)%32: the 4 broadcast groups hit disjoint bank quads (R9 BUG: read
// used copy base without the p<<5 slice offset -> wrong h section, absmax 0.49).
// Dot via v_dot2_f32_bf16; reduce across p: 2-round __shfl_xor; ONE __syncthreads
// per step; zero inter-WG traffic (R1-R7 lesson: MALL exchange floor ~4us/step).
template <typename XPT>
__global__ __launch_bounds__(1024, 4) void lstm_rec(const unsigned* __restrict__ Wh2,
                                                    const XPT* __restrict__ xp,
                                                    float* __restrict__ out) {
  __shared__ unsigned long long wo64[16 * 1024];  // 128KB o-row, column-major
  __shared__ unsigned hb2[2][4][136];             // h pairs, 2 slots x 4 p-copies

  const int tid = threadIdx.x;
  const int b = blockIdx.x;
  const int u = tid >> 2, p = tid & 3;

  // ---- f,i,g rows: volatile-asm loads into 24 named u32x4 (96 VGPRs, pinned)
  const unsigned* wf_p = Wh2 + (size_t)(0 * 256 + u) * 128 + (p << 5);
  const unsigned* wi_p = Wh2 + (size_t)(1 * 256 + u) * 128 + (p << 5);
  const unsigned* wg_p = Wh2 + (size_t)(2 * 256 + u) * 128 + (p << 5);
  u32x4 wf0, wf1, wf2, wf3, wf4, wf5, wf6, wf7;
  u32x4 wi0, wi1, wi2, wi3, wi4, wi5, wi6, wi7;
  u32x4 wg0, wg1, wg2, wg3, wg4, wg5, wg6, wg7;
#define LOADROW(P, R0, R1, R2, R3, R4, R5, R6, R7)                    \
  asm volatile("global_load_dwordx4 %0, %8, off\n\t"                  \
               "global_load_dwordx4 %1, %8, off offset:16\n\t"        \
               "global_load_dwordx4 %2, %8, off offset:32\n\t"        \
               "global_load_dwordx4 %3, %8, off offset:48\n\t"        \
               "global_load_dwordx4 %4, %8, off offset:64\n\t"        \
               "global_load_dwordx4 %5, %8, off offset:80\n\t"        \
               "global_load_dwordx4 %6, %8, off offset:96\n\t"        \
               "global_load_dwordx4 %7, %8, off offset:112"           \
               : "=&v"(R0), "=&v"(R1), "=&v"(R2), "=&v"(R3),          \
                 "=&v"(R4), "=&v"(R5), "=&v"(R6), "=&v"(R7)           \
               : "v"(P)                                               \
               : "memory")
  LOADROW(wf_p, wf0, wf1, wf2, wf3, wf4, wf5, wf6, wf7);
  LOADROW(wi_p, wi0, wi1, wi2, wi3, wi4, wi5, wi6, wi7);
  LOADROW(wg_p, wg0, wg1, wg2, wg3, wg4, wg5, wg6, wg7);
#undef LOADROW
  asm volatile("s_waitcnt vmcnt(0)" ::: "memory");

  // ---- o-row -> LDS column-major b64 (conflict-free reads)
  const unsigned* wo_p = Wh2 + (size_t)(3 * 256 + u) * 128 + (p << 5);
#pragma unroll
  for (int j2 = 0; j2 < 16; j2++)
    wo64[(j2 << 10) + tid] = *(const unsigned long long*)(wo_p + (j2 << 1));

  // ---- zero both h slots (all 4 copies)
  for (int i = tid; i < 2 * 4 * 136; i += 1024) ((unsigned*)hb2)[i] = 0u;

  const size_t xpb = (size_t)b << 10;
  float xv0, xv1, xv2, xv3;
  {
    const XPT* xr = &xp[xpb * 1024 + u];
    xv0 = xp_load(xr); xv1 = xp_load(xr + 256);
    xv2 = xp_load(xr + 512); xv3 = xp_load(xr + 768);
  }
  float c = 0.f;
  __syncthreads();

  for (int t = 0; t < 1024; t++) {
    // R9 FIX: group p reads its own k-slice (pairs 32p..32p+31) of its p-copy
    const unsigned* hrow = &hb2[(t + 1) & 1][p][p << 5];  // (t-1)&1 == (t+1)&1

    float a0 = 0.f, a1 = 0.f, a2 = 0.f, a3 = 0.f;
#define DOT2(ACC, WD, HD) \
  asm("v_dot2_f32_bf16 %0, %1, %2, %0" : "+v"(ACC) : "v"(WD), "v"(HD))
#define STEPJ(J, WF, WI, WG)                                                \
  {                                                                         \
    u32x4 hj = *(const u32x4*)(hrow + ((J) << 2));                          \
    unsigned long long o01 = wo64[((((J) << 1) + 0) << 10) + tid];          \
    unsigned long long o23 = wo64[((((J) << 1) + 1) << 10) + tid];          \
    DOT2(a0, WF[0], hj[0]); DOT2(a0, WF[1], hj[1]);                         \
    DOT2(a0, WF[2], hj[2]); DOT2(a0, WF[3], hj[3]);                         \
    DOT2(a1, WI[0], hj[0]); DOT2(a1, WI[1], hj[1]);                         \
    DOT2(a1, WI[2], hj[2]); DOT2(a1, WI[3], hj[3]);                         \
    DOT2(a2, WG[0], hj[0]); DOT2(a2, WG[1], hj[1]);                         \
    DOT2(a2, WG[2], hj[2]); DOT2(a2, WG[3], hj[3]);                         \
    DOT2(a3, (unsigned)o01, hj[0]); DOT2(a3, (unsigned)(o01 >> 32), hj[1]); \
    DOT2(a3, (unsigned)o23, hj[2]); DOT2(a3, (unsigned)(o23 >> 32), hj[3]); \
  }
    STEPJ(0, wf0, wi0, wg0) STEPJ(1, wf1, wi1, wg1)
    STEPJ(2, wf2, wi2, wg2) STEPJ(3, wf3, wi3, wg3)
    STEPJ(4, wf4, wi4, wg4) STEPJ(5, wf5, wi5, wg5)
    STEPJ(6, wf6, wi6, wg6) STEPJ(7, wf7, wi7, wg7)
#undef STEPJ
#undef DOT2

    // reduce over the 4 p-lanes (adjacent lanes)
    a0 += __shfl_xor(a0, 1, 64); a0 += __shfl_xor(a0, 2, 64);
    a1 += __shfl_xor(a1, 1, 64); a1 += __shfl_xor(a1, 2, 64);
    a2 += __shfl_xor(a2, 1, 64); a2 += __shfl_xor(a2, 2, 64);
    a3 += __shfl_xor(a3, 1, 64); a3 += __shfl_xor(a3, 2, 64);

    float gf = a0 + xv0, gi = a1 + xv1, gg = a2 + xv2, go = a3 + xv3;
    float f = 1.f / (1.f + __expf(-gf));
    float ii = 1.f / (1.f + __expf(-gi));
    float eg = __expf(2.f * gg);
    float gt = (eg - 1.f) / (eg + 1.f);
    float o = 1.f / (1.f + __expf(-go));
    c = f * c + ii * gt;
    float ec = __expf(2.f * c);
    float tc = (ec - 1.f) / (ec + 1.f);
    float h = o * tc;

    // publish h: every p writes its own copy (h computed redundantly in all p lanes)
    float hu1 = __shfl(h, ((tid & 63) + 4) & 63, 64);  // partner unit (u+1), same p
    if ((u & 1) == 0) {
      unsigned dw = (unsigned)f2bf(h) | ((unsigned)f2bf(hu1) << 16);
      hb2[t & 1][p][u >> 1] = dw;
    }
    if (p == 0) {
      __builtin_nontemporal_store(h, &out[(xpb + t) * 256 + u]);
      if (t == 1023) {
        out[16777216 + b * 256 + u] = h;           // h_fin
        out[16777216 + 16384 + b * 256 + u] = c;   // c_fin
      }
    }

    // prefetch next step's xp (one full step of slack -> HBM latency hidden)
    if (t < 1023) {
      const XPT* xr = &xp[(xpb + t + 1) * 1024 + u];
      xv0 = xp_load(xr); xv1 = xp_load(xr + 256);
      xv2 = xp_load(xr + 512); xv3 = xp_load(xr + 768);
    }
    __syncthreads();
  }
}

extern "C" void kernel_launch(void* const* d_in, const int* in_sizes, int n_in,
                              void* d_out, int out_size, void* d_ws, size_t ws_size,
                              hipStream_t stream) {
  (void)in_sizes; (void)n_in; (void)out_size;
  const float* x = (const float*)d_in[0];
  const float* W = (const float*)d_in[1];
  const float* bias = (const float*)d_in[2];
  float* out = (float*)d_out;
  char* ws = (char*)d_ws;

  unsigned int* Wx2 = (unsigned int*)ws;              // 524288 B
  unsigned int* Wh2 = (unsigned int*)(ws + 524288);   // 524288 B
  char* xpmem = ws + 1048576;

  const size_t need32 = 1048576 + (size_t)65536 * 1024 * 4;

  prep_wx<<<512, 256, 0, stream>>>(W, Wx2);
  prep_wh<<<512, 256, 0, stream>>>(W, Wh2);

  if (ws_size >= need32) {
    gemm_xp<float><<<dim3(8, 512), 256, 0, stream>>>(x, Wx2, bias, (float*)xpmem);
    lstm_rec<float><<<64, 1024, 0, stream>>>(Wh2, (const float*)xpmem, out);
  } else {
    gemm_xp<unsigned short><<<dim3(8, 512), 256, 0, stream>>>(x, Wx2, bias,
                                                              (unsigned short*)xpmem);
    lstm_rec<unsigned short><<<64, 1024, 0, stream>>>(Wh2, (const unsigned short*)xpmem, out);
  }
}

// Round 12
// 2361.832 us; speedup vs baseline: 1.1632x; 1.1632x over previous
//
#include <hip/hip_runtime.h>

typedef __attribute__((ext_vector_type(8))) short short8;
typedef __attribute__((ext_vector_type(4))) float f32x4;
typedef __attribute__((ext_vector_type(4))) unsigned u32x4;

__device__ __forceinline__ unsigned short f2bf(float f) {
  unsigned int u = __float_as_uint(f);
  u = (u + 0x7fffu + ((u >> 16) & 1u)) >> 16;
  return (unsigned short)u;
}

__device__ __forceinline__ void xp_store(float* p, float v) { *p = v; }
__device__ __forceinline__ void xp_store(unsigned short* p, float v) { *p = f2bf(v); }

// ---------------- prep: pack W_x and W_h (f32 -> bf16 pairs) ----------------
__global__ void prep_wx(const float* __restrict__ W, unsigned int* __restrict__ Wx2) {
  int i = blockIdx.x * 256 + threadIdx.x;  // 1024*128 dwords
  int g = i >> 7, kk = i & 127;
  float lo = W[(size_t)g * 512 + 256 + 2 * kk];
  float hi = W[(size_t)g * 512 + 256 + 2 * kk + 1];
  Wx2[i] = (unsigned int)f2bf(lo) | ((unsigned int)f2bf(hi) << 16);
}

__global__ void prep_wh(const float* __restrict__ W, unsigned int* __restrict__ Wh2) {
  int i = blockIdx.x * 256 + threadIdx.x;  // 1024*128 dwords
  int r = i >> 7, kk = i & 127;
  float lo = W[(size_t)r * 512 + 2 * kk];
  float hi = W[(size_t)r * 512 + 2 * kk + 1];
  Wh2[i] = (unsigned int)f2bf(lo) | ((unsigned int)f2bf(hi) << 16);
}

// ---------------- GEMM: xp[m][g] = sum_k x[m][k] * Wx[g][k] + b[g] ----------------
template <typename XPT>
__global__ __launch_bounds__(256, 4) void gemm_xp(const float* __restrict__ x,
                                                  const unsigned int* __restrict__ Wx2,
                                                  const float* __restrict__ bias,
                                                  XPT* __restrict__ xp) {
  __shared__ unsigned short As[128][40];
  __shared__ unsigned short Bs[128][40];
  const int m0 = blockIdx.y * 128, n0 = blockIdx.x * 128;
  const int tid = threadIdx.x, lane = tid & 63, w = tid >> 6;
  const int wr = w >> 1, wc = w & 1;
  const int r16 = lane & 15, kq = lane >> 4;
  f32x4 acc[4][4];
#pragma unroll
  for (int m = 0; m < 4; m++)
#pragma unroll
    for (int n = 0; n < 4; n++)
#pragma unroll
      for (int j = 0; j < 4; j++) acc[m][n][j] = 0.f;

  for (int kb = 0; kb < 256; kb += 32) {
    __syncthreads();
#pragma unroll
    for (int i = 0; i < 4; i++) {
      int idx = tid + i * 256;
      int row = idx >> 3, c4 = idx & 7;
      float4 v = *(const float4*)(x + (size_t)(m0 + row) * 256 + kb + c4 * 4);
      ushort4 s;
      s.x = f2bf(v.x); s.y = f2bf(v.y); s.z = f2bf(v.z); s.w = f2bf(v.w);
      *(ushort4*)&As[row][c4 * 4] = s;
    }
#pragma unroll
    for (int i = 0; i < 2; i++) {
      int idx = tid + i * 256;
      int row = idx >> 2, c = idx & 3;
      uint4 v = *(const uint4*)(Wx2 + (size_t)(n0 + row) * 128 + (kb >> 1) + c * 4);
      *(uint4*)&Bs[row][c * 8] = v;
    }
    __syncthreads();
    short8 a[4], bb[4];
#pragma unroll
    for (int m = 0; m < 4; m++)
      a[m] = *(const short8*)&As[wr * 64 + m * 16 + r16][kq * 8];
#pragma unroll
    for (int n = 0; n < 4; n++)
      bb[n] = *(const short8*)&Bs[wc * 64 + n * 16 + r16][kq * 8];
#pragma unroll
    for (int m = 0; m < 4; m++)
#pragma unroll
      for (int n = 0; n < 4; n++)
        acc[m][n] = __builtin_amdgcn_mfma_f32_16x16x32_bf16(a[m], bb[n], acc[m][n], 0, 0, 0);
  }
#pragma unroll
  for (int n = 0; n < 4; n++) {
    int gn = n0 + wc * 64 + n * 16 + r16;
    float bi = bias[gn];
#pragma unroll
    for (int m = 0; m < 4; m++) {
      int gm = m0 + wr * 64 + m * 16 + kq * 4;
#pragma unroll
      for (int j = 0; j < 4; j++) {
        xp_store(&xp[(size_t)(gm + j) * 1024 + gn], acc[m][n][j] + bi);
      }
    }
  }
}

// ---------------- recurrence: ONE BATCH PER CU; demand-engineered <=128 VGPR -------
// 64 WGs x 1024 threads. Thread (u = tid>>2, p = tid&3) owns unit u's four gate rows
// over k-slice [p*64, p*64+64). R8-R10 LESSON: demand (96w + 32h + ~25misc ~ 150)
// exceeded the hard 128-VGPR budget -> allocator spilled the weights -> 384KB/CU/step
// scratch re-reads from L2 (~56 B/cy -> ~6850cy = the observed 2.6us/step).
// R11 cuts true demand under 128: 92 weight dwords in regs (f,i rows + 28 of g);
// o-row + g-tail (36 dwords/thread = 144KB) stream from LDS col-major b128 (the
// unavoidable LDS-resident share: (128-R)/128*512KB must fit in 160KB => R>=92).
// xp staged through LDS (frees 8 regs), h written as ds_write_b16 (no pack temps),
// loop unrolled x2 so all double-buffer slots are compile-time immediates.
// Live ~100 + transients ~24 <= 128. TELL: VGPR_Count ~110-128 (64 => spilled again).
// (R11 compile fix: h-read slot is now an explicit DOTJ parameter -- nested macro
// bodies don't see the outer macro's parameters.)
template <typename XPT>
__global__ __launch_bounds__(1024, 4) void lstm_rec(const unsigned* __restrict__ Wh2,
                                                    const XPT* __restrict__ xp,
                                                    float* __restrict__ out) {
  constexpr bool F32 = sizeof(XPT) == 4;
  __shared__ u32x4 wot[9 * 1024];          // 147456B: o-row (8) + g-tail (1), col-major
  __shared__ unsigned hsh[2][4][136];      // 4352B: h bf16-pairs, 2 slots x 4 p-copies
  __shared__ unsigned xps[2][1024];        // 8192B: xp staging, double-buffered

  const int tid = threadIdx.x;
  const int b = blockIdx.x;
  const int u = tid >> 2, p = tid & 3;
  const int brow0 = b << 10;

  // ---- weight register loads: f,i full rows + g pairs 0..27 (92 dwords)
  const unsigned* wf_p = Wh2 + (size_t)(0 * 256 + u) * 128 + (p << 5);
  const unsigned* wi_p = Wh2 + (size_t)(1 * 256 + u) * 128 + (p << 5);
  const unsigned* wg_p = Wh2 + (size_t)(2 * 256 + u) * 128 + (p << 5);
  const unsigned* wo_p = Wh2 + (size_t)(3 * 256 + u) * 128 + (p << 5);
  u32x4 wf0, wf1, wf2, wf3, wf4, wf5, wf6, wf7;
  u32x4 wi0, wi1, wi2, wi3, wi4, wi5, wi6, wi7;
  u32x4 wg0, wg1, wg2, wg3, wg4, wg5, wg6;
#define LOADROW8(P, R0, R1, R2, R3, R4, R5, R6, R7)                   \
  asm volatile("global_load_dwordx4 %0, %8, off\n\t"                  \
               "global_load_dwordx4 %1, %8, off offset:16\n\t"        \
               "global_load_dwordx4 %2, %8, off offset:32\n\t"        \
               "global_load_dwordx4 %3, %8, off offset:48\n\t"        \
               "global_load_dwordx4 %4, %8, off offset:64\n\t"        \
               "global_load_dwordx4 %5, %8, off offset:80\n\t"        \
               "global_load_dwordx4 %6, %8, off offset:96\n\t"        \
               "global_load_dwordx4 %7, %8, off offset:112"           \
               : "=&v"(R0), "=&v"(R1), "=&v"(R2), "=&v"(R3),          \
                 "=&v"(R4), "=&v"(R5), "=&v"(R6), "=&v"(R7)           \
               : "v"(P)                                               \
               : "memory")
#define LOADROW7(P, R0, R1, R2, R3, R4, R5, R6)                       \
  asm volatile("global_load_dwordx4 %0, %7, off\n\t"                  \
               "global_load_dwordx4 %1, %7, off offset:16\n\t"        \
               "global_load_dwordx4 %2, %7, off offset:32\n\t"        \
               "global_load_dwordx4 %3, %7, off offset:48\n\t"        \
               "global_load_dwordx4 %4, %7, off offset:64\n\t"        \
               "global_load_dwordx4 %5, %7, off offset:80\n\t"        \
               "global_load_dwordx4 %6, %7, off offset:96"            \
               : "=&v"(R0), "=&v"(R1), "=&v"(R2), "=&v"(R3),          \
                 "=&v"(R4), "=&v"(R5), "=&v"(R6)                      \
               : "v"(P)                                               \
               : "memory")
  LOADROW8(wf_p, wf0, wf1, wf2, wf3, wf4, wf5, wf6, wf7);
  LOADROW8(wi_p, wi0, wi1, wi2, wi3, wi4, wi5, wi6, wi7);
  LOADROW7(wg_p, wg0, wg1, wg2, wg3, wg4, wg5, wg6);
#undef LOADROW8
#undef LOADROW7
  asm volatile("s_waitcnt vmcnt(0)" ::: "memory");

  // ---- LDS weight staging: o-row chunks (E=0..7) + g tail (E=8), col-major
#pragma unroll
  for (int E = 0; E < 8; E++) wot[(E << 10) + tid] = *(const u32x4*)(wo_p + (E << 2));
  wot[(8 << 10) + tid] = *(const u32x4*)(wg_p + 28);

  // ---- zero both h slots; stage xp row 0 into xps slot 0
  for (int i = tid; i < 2 * 4 * 136; i += 1024) ((unsigned*)hsh)[i] = 0u;
  if constexpr (F32) {
    xps[0][tid] = ((const unsigned*)xp)[((size_t)brow0 << 10) + tid];
  } else {
    if (tid < 512) xps[0][tid] = ((const unsigned*)xp)[((size_t)brow0 << 9) + tid];
  }
  float c = 0.f;
  float* outp = out + ((size_t)brow0 << 8);
  __syncthreads();

#define DOT2(ACC, WD, HD) \
  asm("v_dot2_f32_bf16 %0, %1, %2, %0" : "+v"(ACC) : "v"(WD), "v"(HD))
#define DOTJ(J, WF, WI, WGQ, HRX)                                   \
  {                                                                 \
    u32x4 hj = *(const u32x4*)&hsh[HRX][p][(p << 5) + ((J) << 2)];  \
    u32x4 oj = wot[((J) << 10) + tid];                              \
    DOT2(a0, WF[0], hj[0]); DOT2(a0, WF[1], hj[1]);                 \
    DOT2(a0, WF[2], hj[2]); DOT2(a0, WF[3], hj[3]);                 \
    DOT2(a1, WI[0], hj[0]); DOT2(a1, WI[1], hj[1]);                 \
    DOT2(a1, WI[2], hj[2]); DOT2(a1, WI[3], hj[3]);                 \
    DOT2(a2, (WGQ)[0], hj[0]); DOT2(a2, (WGQ)[1], hj[1]);           \
    DOT2(a2, (WGQ)[2], hj[2]); DOT2(a2, (WGQ)[3], hj[3]);           \
    DOT2(a3, oj[0], hj[0]); DOT2(a3, oj[1], hj[1]);                 \
    DOT2(a3, oj[2], hj[2]); DOT2(a3, oj[3], hj[3]);                 \
  }

#define STEP(T, HR, HW, XR, XW)                                                        \
  {                                                                                    \
    const int t = (T);                                                                 \
    /* stage xp[t+1]: issue global load early (consumed ~2000cy later) */              \
    unsigned stv = 0u;                                                                 \
    bool do_stage;                                                                     \
    if constexpr (F32) {                                                               \
      do_stage = (t < 1023);                                                           \
      if (do_stage) stv = ((const unsigned*)xp)[((size_t)(brow0 + t + 1) << 10) + tid];\
    } else {                                                                           \
      do_stage = (t < 1023) && (tid < 512);                                            \
      if (do_stage) stv = ((const unsigned*)xp)[((size_t)(brow0 + t + 1) << 9) + tid]; \
    }                                                                                  \
    float a0 = 0.f, a1 = 0.f, a2 = 0.f, a3 = 0.f;                                      \
    DOTJ(0, wf0, wi0, wg0, HR) DOTJ(1, wf1, wi1, wg1, HR)                              \
    DOTJ(2, wf2, wi2, wg2, HR) DOTJ(3, wf3, wi3, wg3, HR)                              \
    DOTJ(4, wf4, wi4, wg4, HR) DOTJ(5, wf5, wi5, wg5, HR)                              \
    DOTJ(6, wf6, wi6, wg6, HR)                                                         \
    {                                                                                  \
      u32x4 gt7 = wot[(8 << 10) + tid];                                                \
      DOTJ(7, wf7, wi7, gt7, HR)                                                       \
    }                                                                                  \
    /* xp values for THIS step from LDS (broadcast reads) */                           \
    float xv0, xv1, xv2, xv3;                                                          \
    if constexpr (F32) {                                                               \
      xv0 = ((const float*)xps)[(XR)*1024 + u];                                        \
      xv1 = ((const float*)xps)[(XR)*1024 + 256 + u];                                  \
      xv2 = ((const float*)xps)[(XR)*1024 + 512 + u];                                  \
      xv3 = ((const float*)xps)[(XR)*1024 + 768 + u];                                  \
    } else {                                                                           \
      unsigned d0 = xps[XR][(u >> 1)];                                                 \
      unsigned d1 = xps[XR][(u >> 1) + 128];                                           \
      unsigned d2 = xps[XR][(u >> 1) + 256];                                           \
      unsigned d3 = xps[XR][(u >> 1) + 384];                                           \
      xv0 = __uint_as_float((u & 1) ? (d0 & 0xFFFF0000u) : (d0 << 16));                \
      xv1 = __uint_as_float((u & 1) ? (d1 & 0xFFFF0000u) : (d1 << 16));                \
      xv2 = __uint_as_float((u & 1) ? (d2 & 0xFFFF0000u) : (d2 << 16));                \
      xv3 = __uint_as_float((u & 1) ? (d3 & 0xFFFF0000u) : (d3 << 16));                \
    }                                                                                  \
    /* reduce over the 4 p-lanes */                                                    \
    a0 += __shfl_xor(a0, 1, 64); a0 += __shfl_xor(a0, 2, 64);                          \
    a1 += __shfl_xor(a1, 1, 64); a1 += __shfl_xor(a1, 2, 64);                          \
    a2 += __shfl_xor(a2, 1, 64); a2 += __shfl_xor(a2, 2, 64);                          \
    a3 += __shfl_xor(a3, 1, 64); a3 += __shfl_xor(a3, 2, 64);                          \
    float gf = a0 + xv0, gi = a1 + xv1, gg = a2 + xv2, go = a3 + xv3;                  \
    float f = 1.f / (1.f + __expf(-gf));                                               \
    float ii = 1.f / (1.f + __expf(-gi));                                              \
    float eg = __expf(2.f * gg);                                                       \
    float gtv = (eg - 1.f) / (eg + 1.f);                                               \
    float o = 1.f / (1.f + __expf(-go));                                               \
    c = f * c + ii * gtv;                                                              \
    float ec = __expf(2.f * c);                                                        \
    float tc = (ec - 1.f) / (ec + 1.f);                                                \
    float h = o * tc;                                                                  \
    /* publish: each lane writes its unit's bf16 into its own p-copy */                \
    ((unsigned short*)&hsh[HW][p][0])[u] = f2bf(h);                                    \
    if (do_stage) xps[XW][tid] = stv;                                                  \
    if (p == 0) {                                                                      \
      __builtin_nontemporal_store(h, outp + ((size_t)t << 8) + u);                     \
      if (t == 1023) {                                                                 \
        out[16777216 + b * 256 + u] = h;                                               \
        out[16777216 + 16384 + b * 256 + u] = c;                                       \
      }                                                                                \
    }                                                                                  \
    __syncthreads();                                                                   \
  }

  for (int t2 = 0; t2 < 1024; t2 += 2) {
    STEP(t2, 1, 0, 0, 1)      // t even: read h slot1, write slot0; xp read 0, stage 1
    STEP(t2 + 1, 0, 1, 1, 0)  // t odd:  read h slot0, write slot1; xp read 1, stage 0
  }
#undef STEP
#undef DOTJ
#undef DOT2
}

extern "C" void kernel_launch(void* const* d_in, const int* in_sizes, int n_in,
                              void* d_out, int out_size, void* d_ws, size_t ws_size,
                              hipStream_t stream) {
  (void)in_sizes; (void)n_in; (void)out_size;
  const float* x = (const float*)d_in[0];
  const float* W = (const float*)d_in[1];
  const float* bias = (const float*)d_in[2];
  float* out = (float*)d_out;
  char* ws = (char*)d_ws;

  unsigned int* Wx2 = (unsigned int*)ws;              // 524288 B
  unsigned int* Wh2 = (unsigned int*)(ws + 524288);   // 524288 B
  char* xpmem = ws + 1048576;

  const size_t need32 = 1048576 + (size_t)65536 * 1024 * 4;

  prep_wx<<<512, 256, 0, stream>>>(W, Wx2);
  prep_wh<<<512, 256, 0, stream>>>(W, Wh2);

  if (ws_size >= need32) {
    gemm_xp<float><<<dim3(8, 512), 256, 0, stream>>>(x, Wx2, bias, (float*)xpmem);
    lstm_rec<float><<<64, 1024, 0, stream>>>(Wh2, (const float*)xpmem, out);
  } else {
    gemm_xp<unsigned short><<<dim3(8, 512), 256, 0, stream>>>(x, Wx2, bias,
                                                              (unsigned short*)xpmem);
    lstm_rec<unsigned short><<<64, 1024, 0, stream>>>(Wh2, (const unsigned short*)xpmem, out);
  }
}

// Round 13
// 2251.768 us; speedup vs baseline: 1.2201x; 1.0489x over previous
//
#include <hip/hip_runtime.h>

typedef __attribute__((ext_vector_type(8))) short short8;
typedef __attribute__((ext_vector_type(4))) float f32x4;
typedef __attribute__((ext_vector_type(4))) unsigned u32x4;

__device__ __forceinline__ unsigned short f2bf(float f) {
  unsigned int u = __float_as_uint(f);
  u = (u + 0x7fffu + ((u >> 16) & 1u)) >> 16;
  return (unsigned short)u;
}

__device__ __forceinline__ void xp_store(float* p, float v) { *p = v; }
__device__ __forceinline__ void xp_store(unsigned short* p, float v) { *p = f2bf(v); }

// quad reduce via DPP (VALU pipe, no DS): sum over the 4 lanes of each quad.
// quad_perm[1,0,3,2] = 177 (xor lane-bit0), quad_perm[2,3,0,1] = 78 (xor bit1).
__device__ __forceinline__ float quad_sum(float a) {
  float t1 = __int_as_float(
      __builtin_amdgcn_update_dpp(0, __float_as_int(a), 177, 0xf, 0xf, true));
  a += t1;
  float t2 = __int_as_float(
      __builtin_amdgcn_update_dpp(0, __float_as_int(a), 78, 0xf, 0xf, true));
  return a + t2;
}

// ---------------- prep: pack W_x and W_h (f32 -> bf16 pairs) ----------------
__global__ void prep_wx(const float* __restrict__ W, unsigned int* __restrict__ Wx2) {
  int i = blockIdx.x * 256 + threadIdx.x;  // 1024*128 dwords
  int g = i >> 7, kk = i & 127;
  float lo = W[(size_t)g * 512 + 256 + 2 * kk];
  float hi = W[(size_t)g * 512 + 256 + 2 * kk + 1];
  Wx2[i] = (unsigned int)f2bf(lo) | ((unsigned int)f2bf(hi) << 16);
}

__global__ void prep_wh(const float* __restrict__ W, unsigned int* __restrict__ Wh2) {
  int i = blockIdx.x * 256 + threadIdx.x;  // 1024*128 dwords
  int r = i >> 7, kk = i & 127;
  float lo = W[(size_t)r * 512 + 2 * kk];
  float hi = W[(size_t)r * 512 + 2 * kk + 1];
  Wh2[i] = (unsigned int)f2bf(lo) | ((unsigned int)f2bf(hi) << 16);
}

// ---------------- GEMM: xp[m][g] = sum_k x[m][k] * Wx[g][k] + b[g] ----------------
template <typename XPT>
__global__ __launch_bounds__(256, 4) void gemm_xp(const float* __restrict__ x,
                                                  const unsigned int* __restrict__ Wx2,
                                                  const float* __restrict__ bias,
                                                  XPT* __restrict__ xp) {
  __shared__ unsigned short As[128][40];
  __shared__ unsigned short Bs[128][40];
  const int m0 = blockIdx.y * 128, n0 = blockIdx.x * 128;
  const int tid = threadIdx.x, lane = tid & 63, w = tid >> 6;
  const int wr = w >> 1, wc = w & 1;
  const int r16 = lane & 15, kq = lane >> 4;
  f32x4 acc[4][4];
#pragma unroll
  for (int m = 0; m < 4; m++)
#pragma unroll
    for (int n = 0; n < 4; n++)
#pragma unroll
      for (int j = 0; j < 4; j++) acc[m][n][j] = 0.f;

  for (int kb = 0; kb < 256; kb += 32) {
    __syncthreads();
#pragma unroll
    for (int i = 0; i < 4; i++) {
      int idx = tid + i * 256;
      int row = idx >> 3, c4 = idx & 7;
      float4 v = *(const float4*)(x + (size_t)(m0 + row) * 256 + kb + c4 * 4);
      ushort4 s;
      s.x = f2bf(v.x); s.y = f2bf(v.y); s.z = f2bf(v.z); s.w = f2bf(v.w);
      *(ushort4*)&As[row][c4 * 4] = s;
    }
#pragma unroll
    for (int i = 0; i < 2; i++) {
      int idx = tid + i * 256;
      int row = idx >> 2, c = idx & 3;
      uint4 v = *(const uint4*)(Wx2 + (size_t)(n0 + row) * 128 + (kb >> 1) + c * 4);
      *(uint4*)&Bs[row][c * 8] = v;
    }
    __syncthreads();
    short8 a[4], bb[4];
#pragma unroll
    for (int m = 0; m < 4; m++)
      a[m] = *(const short8*)&As[wr * 64 + m * 16 + r16][kq * 8];
#pragma unroll
    for (int n = 0; n < 4; n++)
      bb[n] = *(const short8*)&Bs[wc * 64 + n * 16 + r16][kq * 8];
#pragma unroll
    for (int m = 0; m < 4; m++)
#pragma unroll
      for (int n = 0; n < 4; n++)
        acc[m][n] = __builtin_amdgcn_mfma_f32_16x16x32_bf16(a[m], bb[n], acc[m][n], 0, 0, 0);
  }
#pragma unroll
  for (int n = 0; n < 4; n++) {
    int gn = n0 + wc * 64 + n * 16 + r16;
    float bi = bias[gn];
#pragma unroll
    for (int m = 0; m < 4; m++) {
      int gm = m0 + wr * 64 + m * 16 + kq * 4;
#pragma unroll
      for (int j = 0; j < 4; j++) {
        xp_store(&xp[(size_t)(gm + j) * 1024 + gn], acc[m][n][j] + bi);
      }
    }
  }
}

// ---------------- recurrence: ONE BATCH PER CU; pinned 4 waves/EU ------------------
// 64 WGs x 1024 threads. Thread (u = tid>>2, p = tid&3) owns unit u's four gate rows
// over k-slice [p*64, p*64+64). R12 LESSON: __launch_bounds__ only sets MIN waves/EU;
// the allocator still targeted 8/EU (64 VGPRs) and shoved the overflow into AGPR
// moves. amdgpu_waves_per_eu(4,4) pins min=max=4 -> full 128-VGPR budget (LDS already
// caps us at 1 WG/CU, so extra occupancy was unusable anyway). TELL: VGPR_Count>=100.
// 92 weight dwords in regs (f,i rows + 28 of g); o-row + g-tail (36 dwords/thread =
// 144KB) stream from LDS col-major b128. xp staged through LDS. h: bf16 pairs, 2
// slots x 4 p-copies (conflict-free, verified R12). p-reduce now via DPP quad_perm
// (VALU pipe) instead of __shfl_xor (DS pipe): removes 128 DS insts/CU/step and two
// ~120cy DS latencies from the serial chain. DOTJ issues the full-BW oj read before
// the broadcast hj read so the DS pipe fills right after barrier release.
template <typename XPT>
__global__ __attribute__((amdgpu_flat_work_group_size(1024, 1024),
                          amdgpu_waves_per_eu(4, 4)))
void lstm_rec(const unsigned* __restrict__ Wh2,
              const XPT* __restrict__ xp,
              float* __restrict__ out) {
  constexpr bool F32 = sizeof(XPT) == 4;
  __shared__ u32x4 wot[9 * 1024];          // 147456B: o-row (8) + g-tail (1), col-major
  __shared__ unsigned hsh[2][4][136];      // 4352B: h bf16-pairs, 2 slots x 4 p-copies
  __shared__ unsigned xps[2][1024];        // 8192B: xp staging, double-buffered

  const int tid = threadIdx.x;
  const int b = blockIdx.x;
  const int u = tid >> 2, p = tid & 3;
  const int brow0 = b << 10;

  // ---- weight register loads: f,i full rows + g pairs 0..27 (92 dwords)
  const unsigned* wf_p = Wh2 + (size_t)(0 * 256 + u) * 128 + (p << 5);
  const unsigned* wi_p = Wh2 + (size_t)(1 * 256 + u) * 128 + (p << 5);
  const unsigned* wg_p = Wh2 + (size_t)(2 * 256 + u) * 128 + (p << 5);
  const unsigned* wo_p = Wh2 + (size_t)(3 * 256 + u) * 128 + (p << 5);
  u32x4 wf0, wf1, wf2, wf3, wf4, wf5, wf6, wf7;
  u32x4 wi0, wi1, wi2, wi3, wi4, wi5, wi6, wi7;
  u32x4 wg0, wg1, wg2, wg3, wg4, wg5, wg6;
#define LOADROW8(P, R0, R1, R2, R3, R4, R5, R6, R7)                   \
  asm volatile("global_load_dwordx4 %0, %8, off\n\t"                  \
               "global_load_dwordx4 %1, %8, off offset:16\n\t"        \
               "global_load_dwordx4 %2, %8, off offset:32\n\t"        \
               "global_load_dwordx4 %3, %8, off offset:48\n\t"        \
               "global_load_dwordx4 %4, %8, off offset:64\n\t"        \
               "global_load_dwordx4 %5, %8, off offset:80\n\t"        \
               "global_load_dwordx4 %6, %8, off offset:96\n\t"        \
               "global_load_dwordx4 %7, %8, off offset:112"           \
               : "=&v"(R0), "=&v"(R1), "=&v"(R2), "=&v"(R3),          \
                 "=&v"(R4), "=&v"(R5), "=&v"(R6), "=&v"(R7)           \
               : "v"(P)                                               \
               : "memory")
#define LOADROW7(P, R0, R1, R2, R3, R4, R5, R6)                       \
  asm volatile("global_load_dwordx4 %0, %7, off\n\t"                  \
               "global_load_dwordx4 %1, %7, off offset:16\n\t"        \
               "global_load_dwordx4 %2, %7, off offset:32\n\t"        \
               "global_load_dwordx4 %3, %7, off offset:48\n\t"        \
               "global_load_dwordx4 %4, %7, off offset:64\n\t"        \
               "global_load_dwordx4 %5, %7, off offset:80\n\t"        \
               "global_load_dwordx4 %6, %7, off offset:96"            \
               : "=&v"(R0), "=&v"(R1), "=&v"(R2), "=&v"(R3),          \
                 "=&v"(R4), "=&v"(R5), "=&v"(R6)                      \
               : "v"(P)                                               \
               : "memory")
  LOADROW8(wf_p, wf0, wf1, wf2, wf3, wf4, wf5, wf6, wf7);
  LOADROW8(wi_p, wi0, wi1, wi2, wi3, wi4, wi5, wi6, wi7);
  LOADROW7(wg_p, wg0, wg1, wg2, wg3, wg4, wg5, wg6);
#undef LOADROW8
#undef LOADROW7
  asm volatile("s_waitcnt vmcnt(0)" ::: "memory");

  // ---- LDS weight staging: o-row chunks (E=0..7) + g tail (E=8), col-major
#pragma unroll
  for (int E = 0; E < 8; E++) wot[(E << 10) + tid] = *(const u32x4*)(wo_p + (E << 2));
  wot[(8 << 10) + tid] = *(const u32x4*)(wg_p + 28);

  // ---- zero both h slots; stage xp row 0 into xps slot 0
  for (int i = tid; i < 2 * 4 * 136; i += 1024) ((unsigned*)hsh)[i] = 0u;
  if constexpr (F32) {
    xps[0][tid] = ((const unsigned*)xp)[((size_t)brow0 << 10) + tid];
  } else {
    if (tid < 512) xps[0][tid] = ((const unsigned*)xp)[((size_t)brow0 << 9) + tid];
  }
  float c = 0.f;
  float* outp = out + ((size_t)brow0 << 8);
  __syncthreads();

#define DOT2(ACC, WD, HD) \
  asm("v_dot2_f32_bf16 %0, %1, %2, %0" : "+v"(ACC) : "v"(WD), "v"(HD))
#define DOTJ(J, WF, WI, WGQ, HRX)                                   \
  {                                                                 \
    u32x4 oj = wot[((J) << 10) + tid];                              \
    u32x4 hj = *(const u32x4*)&hsh[HRX][p][(p << 5) + ((J) << 2)];  \
    DOT2(a0, WF[0], hj[0]); DOT2(a0, WF[1], hj[1]);                 \
    DOT2(a0, WF[2], hj[2]); DOT2(a0, WF[3], hj[3]);                 \
    DOT2(a1, WI[0], hj[0]); DOT2(a1, WI[1], hj[1]);                 \
    DOT2(a1, WI[2], hj[2]); DOT2(a1, WI[3], hj[3]);                 \
    DOT2(a2, (WGQ)[0], hj[0]); DOT2(a2, (WGQ)[1], hj[1]);           \
    DOT2(a2, (WGQ)[2], hj[2]); DOT2(a2, (WGQ)[3], hj[3]);           \
    DOT2(a3, oj[0], hj[0]); DOT2(a3, oj[1], hj[1]);                 \
    DOT2(a3, oj[2], hj[2]); DOT2(a3, oj[3], hj[3]);                 \
  }

#define STEP(T, HR, HW, XR, XW)                                                        \
  {                                                                                    \
    const int t = (T);                                                                 \
    /* stage xp[t+1]: issue global load early (consumed ~2000cy later) */              \
    unsigned stv = 0u;                                                                 \
    bool do_stage;                                                                     \
    if constexpr (F32) {                                                               \
      do_stage = (t < 1023);                                                           \
      if (do_stage) stv = ((const unsigned*)xp)[((size_t)(brow0 + t + 1) << 10) + tid];\
    } else {                                                                           \
      do_stage = (t < 1023) && (tid < 512);                                            \
      if (do_stage) stv = ((const unsigned*)xp)[((size_t)(brow0 + t + 1) << 9) + tid]; \
    }                                                                                  \
    float a0 = 0.f, a1 = 0.f, a2 = 0.f, a3 = 0.f;                                      \
    DOTJ(0, wf0, wi0, wg0, HR) DOTJ(1, wf1, wi1, wg1, HR)                              \
    DOTJ(2, wf2, wi2, wg2, HR) DOTJ(3, wf3, wi3, wg3, HR)                              \
    DOTJ(4, wf4, wi4, wg4, HR) DOTJ(5, wf5, wi5, wg5, HR)                              \
    DOTJ(6, wf6, wi6, wg6, HR)                                                         \
    {                                                                                  \
      u32x4 gt7 = wot[(8 << 10) + tid];                                                \
      DOTJ(7, wf7, wi7, gt7, HR)                                                       \
    }                                                                                  \
    /* xp values for THIS step from LDS (broadcast reads) */                           \
    float xv0, xv1, xv2, xv3;                                                          \
    if constexpr (F32) {                                                               \
      xv0 = ((const float*)xps)[(XR)*1024 + u];                                        \
      xv1 = ((const float*)xps)[(XR)*1024 + 256 + u];                                  \
      xv2 = ((const float*)xps)[(XR)*1024 + 512 + u];                                  \
      xv3 = ((const float*)xps)[(XR)*1024 + 768 + u];                                  \
    } else {                                                                           \
      unsigned d0 = xps[XR][(u >> 1)];                                                 \
      unsigned d1 = xps[XR][(u >> 1) + 128];                                           \
      unsigned d2 = xps[XR][(u >> 1) + 256];                                           \
      unsigned d3 = xps[XR][(u >> 1) + 384];                                           \
      xv0 = __uint_as_float((u & 1) ? (d0 & 0xFFFF0000u) : (d0 << 16));                \
      xv1 = __uint_as_float((u & 1) ? (d1 & 0xFFFF0000u) : (d1 << 16));                \
      xv2 = __uint_as_float((u & 1) ? (d2 & 0xFFFF0000u) : (d2 << 16));                \
      xv3 = __uint_as_float((u & 1) ? (d3 & 0xFFFF0000u) : (d3 << 16));                \
    }                                                                                  \
    /* reduce over the 4 p-lanes: DPP quad_perm adds (VALU pipe, no DS) */             \
    a0 = quad_sum(a0); a1 = quad_sum(a1); a2 = quad_sum(a2); a3 = quad_sum(a3);        \
    float gf = a0 + xv0, gi = a1 + xv1, gg = a2 + xv2, go = a3 + xv3;                  \
    float f = 1.f / (1.f + __expf(-gf));                                               \
    float ii = 1.f / (1.f + __expf(-gi));                                              \
    float eg = __expf(2.f * gg);                                                       \
    float gtv = (eg - 1.f) / (eg + 1.f);                                               \
    float o = 1.f / (1.f + __expf(-go));                                               \
    c = f * c + ii * gtv;                                                              \
    float ec = __expf(2.f * c);                                                        \
    float tc = (ec - 1.f) / (ec + 1.f);                                                \
    float h = o * tc;                                                                  \
    /* publish: each lane writes its unit's bf16 into its own p-copy */                \
    ((unsigned short*)&hsh[HW][p][0])[u] = f2bf(h);                                    \
    if (do_stage) xps[XW][tid] = stv;                                                  \
    if (p == 0) {                                                                      \
      __builtin_nontemporal_store(h, outp + ((size_t)t << 8) + u);                     \
      if (t == 1023) {                                                                 \
        out[16777216 + b * 256 + u] = h;                                               \
        out[16777216 + 16384 + b * 256 + u] = c;                                       \
      }                                                                                \
    }                                                                                  \
    __syncthreads();                                                                   \
  }

  for (int t2 = 0; t2 < 1024; t2 += 2) {
    STEP(t2, 1, 0, 0, 1)      // t even: read h slot1, write slot0; xp read 0, stage 1
    STEP(t2 + 1, 0, 1, 1, 0)  // t odd:  read h slot0, write slot1; xp read 1, stage 0
  }
#undef STEP
#undef DOTJ
#undef DOT2
}

extern "C" void kernel_launch(void* const* d_in, const int* in_sizes, int n_in,
                              void* d_out, int out_size, void* d_ws, size_t ws_size,
                              hipStream_t stream) {
  (void)in_sizes; (void)n_in; (void)out_size;
  const float* x = (const float*)d_in[0];
  const float* W = (const float*)d_in[1];
  const float* bias = (const float*)d_in[2];
  float* out = (float*)d_out;
  char* ws = (char*)d_ws;

  unsigned int* Wx2 = (unsigned int*)ws;              // 524288 B
  unsigned int* Wh2 = (unsigned int*)(ws + 524288);   // 524288 B
  char* xpmem = ws + 1048576;

  const size_t need32 = 1048576 + (size_t)65536 * 1024 * 4;

  prep_wx<<<512, 256, 0, stream>>>(W, Wx2);
  prep_wh<<<512, 256, 0, stream>>>(W, Wh2);

  if (ws_size >= need32) {
    gemm_xp<float><<<dim3(8, 512), 256, 0, stream>>>(x, Wx2, bias, (float*)xpmem);
    lstm_rec<float><<<64, 1024, 0, stream>>>(Wh2, (const float*)xpmem, out);
  } else {
    gemm_xp<unsigned short><<<dim3(8, 512), 256, 0, stream>>>(x, Wx2, bias,
                                                              (unsigned short*)xpmem);
    lstm_rec<unsigned short><<<64, 1024, 0, stream>>>(Wh2, (const unsigned short*)xpmem, out);
  }
}